// Round 6
// baseline (479.137 us; speedup 1.0000x reference)
//
#include <hip/hip_runtime.h>
#include <hip/hip_bf16.h>
#include <stdint.h>

// ---------- types ----------
typedef __attribute__((ext_vector_type(8)))  short bf16x8;   // MFMA A/B frag (4 VGPR)
typedef __attribute__((ext_vector_type(16))) float f32x16;   // 32x32 MFMA C/D frag

__device__ __forceinline__ unsigned short f2bf(float f) {
  unsigned int u = __float_as_uint(f);
  u += 0x7FFFu + ((u >> 16) & 1u);   // round-to-nearest-even
  return (unsigned short)(u >> 16);
}

__device__ __forceinline__ void async_cp16(const void* g, void* l) {
  __builtin_amdgcn_global_load_lds((const __attribute__((address_space(1))) void*)g,
                                   (__attribute__((address_space(3))) void*)l,
                                   16, 0, 0);
}

// ---------- fp32 -> bf16 conversion (memory-bound, vectorized) ----------
__global__ __launch_bounds__(256) void cvt_f32_to_bf16(const float* __restrict__ in,
                                                       unsigned short* __restrict__ out,
                                                       int n4) {
  int i = blockIdx.x * blockDim.x + threadIdx.x;
  const int stride = gridDim.x * blockDim.x;
  for (; i < n4; i += stride) {
    const float4 v = ((const float4*)in)[i];
    ushort4 o;
    o.x = f2bf(v.x); o.y = f2bf(v.y); o.z = f2bf(v.z); o.w = f2bf(v.w);
    ((ushort4*)out)[i] = o;
  }
}

// ---------- fp32 -> bf16 with gate/up row interleave (64-row groups) ----------
// out row r: g = r>>6, w = r&63; src = g*32 + (w&31) + (w>=32 ? 2048 : 0)
// -> each 64-row group = 32 gate rows + 32 up rows of the same 32-wide e-block,
// so adjacent 32x32 MFMA n-tiles pair gate/up IN-LANE (col = lane&31 matches).
__global__ __launch_bounds__(256) void cvt_wug_perm(const float* __restrict__ in,
                                                    unsigned short* __restrict__ out,
                                                    int n4) {            // 4096*1792
  int i = blockIdx.x * blockDim.x + threadIdx.x;
  const int stride = gridDim.x * blockDim.x;
  for (; i < n4; i += stride) {
    const int r = i / 1792, c = i - r * 1792;
    const int g = r >> 6, w = r & 63;
    const int src = g * 32 + (w & 31) + ((w & 32) ? 2048 : 0);
    const float4 v = ((const float4*)in)[(size_t)src * 1792 + c];
    ushort4 o;
    o.x = f2bf(v.x); o.y = f2bf(v.y); o.z = f2bf(v.z); o.w = f2bf(v.w);
    ((ushort4*)out)[(size_t)r * 1792 + c] = o;
  }
}

// ---------- 256x256 NT bf16 GEMM, 4 waves, wave-tile 128x128, mfma 32x32x16 --
// C[m,n] = sum_k A[m,k]*B[n,k].  256 thr = 4 waves (2Mx2N). acc = 4x4 f32x16.
// 1 wave/SIMD: each wave's 16-MFMA cluster drains ~512 cyc on the matrix unit
// while the wave itself issues the next cluster's ds_reads + staging -> pipes
// self-overlap without cross-wave phase lockstep (the round-3 52% stall).
// LDS ring-3 at kstep (BK=32) granularity: slot = 16K A + 16K B = 96 KiB.
// Per kstep: 8 staging gloads (4 A early, 4 B mid), 16 ds_read_b128,
// 32 MFMA in 2 clusters, ONE vmcnt(8) (counted, never 0) + s_barrier.
// Swizzle: line L (128B) = rows 2L,2L+1; physical 16B-slot p holds logical
// q = p ^ (L&7), q = parity*4 + slotc. Staging pre-swizzles the per-lane
// GLOBAL source; LDS dest stays linear (m173). Read side: even 8-lanes-per-
// bank-quad spread -> conflict-free.
// 32x32x16 frag layouts: A/B lane l: row/col = l&31, k = (l>>5)*8 + j (+16*kh)
// C/D: col = lane&31, row = (reg&3) + 8*(reg>>2) + 4*(lane>>5)  [m74/m101].
// FUSE_SWIGLU: B pre-permuted (64-row groups) -> n-tile 2t = gate, 2t+1 = up,
// same e-cols in-lane; h = silu(g)*u, write [M, N/2] bf16.
template <int K, int N, bool FUSE_SWIGLU>
__global__ __launch_bounds__(256, 1) void gemm_nt(const unsigned short* __restrict__ A,
                                                  const unsigned short* __restrict__ B,
                                                  void* __restrict__ Cv) {
  extern __shared__ char sm[];   // 98304 B: 3 slots x (16K A | 16K B)
  constexpr int nbx = N / 256;
  constexpr int nwg = (4096 / 256) * nbx;
  constexpr size_t K2 = (size_t)K * 2;
  constexpr int nh = K / 32;     // ksteps

  // T1: bijective XCD swizzle (nwg % 8 == 0 for both GEMMs)
  const int bid = blockIdx.x;
  constexpr int q8 = nwg / 8;
  const int swz = (bid & 7) * q8 + (bid >> 3);
  const int bx = swz % nbx, by = swz / nbx;
  const int row0 = by * 256, col0 = bx * 256;

  const int tid = threadIdx.x, wave = tid >> 6, lane = tid & 63;
  const int wr = wave >> 1, wc = wave & 1;       // wave 2x2 grid
  const int l31 = lane & 31, hi = lane >> 5;

  // ---- staging setup: 4 A + 4 B gloads per thread per kstep ----
  const int p7 = lane & 7, l3 = lane >> 3;
  const int qs  = p7 ^ l3;            // logical slot this lane stages
  const int qr  = qs >> 2;            // row parity
  const int qc  = (qs & 3) * 16;      // 16B col within the row's 64B kstep span
  int offsA[4], offsB[4], dstOff[4];
#pragma unroll
  for (int i = 0; i < 4; ++i) {
    const int j = wave * 4 + i;       // chunk 0..15 (8 lines = 1 KiB each)
    const int L = j * 8 + l3;         // LDS line 0..127
    offsA[i] = (row0 + 2 * L + qr) * (int)K2 + qc;
    offsB[i] = (col0 + 2 * L + qr) * (int)K2 + qc;
    dstOff[i] = j * 1024 + lane * 16;
  }
  const char* Ab = (const char*)A;
  const char* Bb = (const char*)B;

  // ---- fragment read offsets (swizzled); line = wr*64 + mt*16 + lin ----
  const int lin = l31 >> 1;                       // line within 32-row tile
  const int qb  = (lane & 1) * 4 + hi;            // parity*4 + hi
  const int l7  = lin & 7;
  const int offA[2] = { (wr * 64 + lin) * 128 + ((qb    ) ^ l7) * 16,
                        (wr * 64 + lin) * 128 + ((qb + 2) ^ l7) * 16 };
  const int offB[2] = { (wc * 64 + lin) * 128 + ((qb    ) ^ l7) * 16,
                        (wc * 64 + lin) * 128 + ((qb + 2) ^ l7) * 16 };

  f32x16 acc[4][4];
#pragma unroll
  for (int m = 0; m < 4; ++m)
#pragma unroll
    for (int n = 0; n < 4; ++n)
#pragma unroll
      for (int j = 0; j < 16; ++j) acc[m][n][j] = 0.f;

#define STAGE_A(hh, slot) do {                                              \
    _Pragma("unroll")                                                       \
    for (int i_ = 0; i_ < 4; ++i_)                                          \
      async_cp16(Ab + offsA[i_] + (size_t)(hh) * 64,                        \
                 sm + (slot) * 32768 + dstOff[i_]);                         \
  } while (0)
#define STAGE_B(hh, slot) do {                                              \
    _Pragma("unroll")                                                       \
    for (int i_ = 0; i_ < 4; ++i_)                                          \
      async_cp16(Bb + offsB[i_] + (size_t)(hh) * 64,                        \
                 sm + (slot) * 32768 + 16384 + dstOff[i_]);                 \
  } while (0)

  // prologue: stage ksteps 0,1; drain kstep 0's 8 loads -> slot 0 ready
  STAGE_A(0, 0); STAGE_B(0, 0);
  STAGE_A(1, 1); STAGE_B(1, 1);
  asm volatile("s_waitcnt vmcnt(8)" ::: "memory");
  __builtin_amdgcn_s_barrier();

  // invariant at top of kstep h: slot h%3 resident, h+1's loads in flight
  for (int h = 0; h < nh; ++h) {
    const int slot = h % 3;
    const char* aBase = sm + slot * 32768;
    const char* bBase = aBase + 16384;
    const int hs = (h + 2 < nh) ? h + 2 : nh - 1;  // clamp keeps vmcnt count
    const int ss = (h + 2) % 3;                    // last read in kstep h-1

    bf16x8 bfr[4][2], af[2][2];
#pragma unroll
    for (int nt = 0; nt < 4; ++nt)
#pragma unroll
      for (int kh = 0; kh < 2; ++kh)
        bfr[nt][kh] = *(const bf16x8*)(bBase + nt * 2048 + offB[kh]);
#pragma unroll
    for (int mt = 0; mt < 2; ++mt)
#pragma unroll
      for (int kh = 0; kh < 2; ++kh)
        af[mt][kh] = *(const bf16x8*)(aBase + mt * 2048 + offA[kh]);
    STAGE_A(hs, ss);

    __builtin_amdgcn_s_setprio(1);
#pragma unroll
    for (int kh = 0; kh < 2; ++kh)
#pragma unroll
      for (int mt = 0; mt < 2; ++mt)
#pragma unroll
        for (int nt = 0; nt < 4; ++nt)
          acc[mt][nt] = __builtin_amdgcn_mfma_f32_32x32x16_bf16(af[mt][kh], bfr[nt][kh], acc[mt][nt], 0, 0, 0);
    __builtin_amdgcn_s_setprio(0);

#pragma unroll
    for (int mt = 0; mt < 2; ++mt)
#pragma unroll
      for (int kh = 0; kh < 2; ++kh)
        af[mt][kh] = *(const bf16x8*)(aBase + (mt + 2) * 2048 + offA[kh]);
    STAGE_B(hs, ss);

    __builtin_amdgcn_s_setprio(1);
#pragma unroll
    for (int kh = 0; kh < 2; ++kh)
#pragma unroll
      for (int mt = 0; mt < 2; ++mt)
#pragma unroll
        for (int nt = 0; nt < 4; ++nt)
          acc[mt + 2][nt] = __builtin_amdgcn_mfma_f32_32x32x16_bf16(af[mt][kh], bfr[nt][kh], acc[mt + 2][nt], 0, 0, 0);
    __builtin_amdgcn_s_setprio(0);

    // single sync point: kstep h+1's 8 loads drained (16 -> 8 outstanding)
    asm volatile("s_waitcnt vmcnt(8)" ::: "memory");
    __builtin_amdgcn_s_barrier();
  }
#undef STAGE_A
#undef STAGE_B

  // ---- epilogue: C/D col = lane&31, row = (reg&3)+8*(reg>>2)+4*hi ----
  const int rowb = row0 + wr * 128;
  if (FUSE_SWIGLU) {
    unsigned short* Hp = (unsigned short*)Cv;
    const int ecb = ((col0 + wc * 128) >> 1) + l31;
#pragma unroll
    for (int mt = 0; mt < 4; ++mt)
#pragma unroll
      for (int t = 0; t < 2; ++t)
#pragma unroll
        for (int j = 0; j < 16; ++j) {
          const int row = rowb + mt * 32 + (j & 3) + 8 * (j >> 2) + 4 * hi;
          const float gv = acc[mt][2 * t][j];
          const float uv = acc[mt][2 * t + 1][j];
          const float s  = gv / (1.0f + __expf(-gv));
          Hp[(size_t)row * (N / 2) + (ecb + t * 32)] = f2bf(s * uv);
        }
  } else {
    float* Cp = (float*)Cv;
    const int colb = col0 + wc * 128 + l31;
#pragma unroll
    for (int mt = 0; mt < 4; ++mt)
#pragma unroll
      for (int nt = 0; nt < 4; ++nt)
#pragma unroll
        for (int j = 0; j < 16; ++j) {
          const int row = rowb + mt * 32 + (j & 3) + 8 * (j >> 2) + 4 * hi;
          Cp[(size_t)row * N + (colb + nt * 32)] = acc[mt][nt][j];
        }
  }
}

// ---------- launch ----------
extern "C" void kernel_launch(void* const* d_in, const int* in_sizes, int n_in,
                              void* d_out, int out_size, void* d_ws, size_t ws_size,
                              hipStream_t stream) {
  const int M = 4096, K = 7168, E = 2048;

  const float* x   = (const float*)d_in[0];  // [M,K]
  const float* wug = (const float*)d_in[1];  // [2E,K]
  const float* wd  = (const float*)d_in[2];  // [K,E]
  float* out = (float*)d_out;                // [M,K]

  // workspace layout (bytes)
  char* ws = (char*)d_ws;
  unsigned short* xb  = (unsigned short*)(ws);               //  58,720,256
  unsigned short* wub = (unsigned short*)(ws + 58720256);    //  58,720,256 (permuted)
  unsigned short* wdb = (unsigned short*)(ws + 117440512);   //  29,360,128
  unsigned short* h   = (unsigned short*)(ws + 146800640);   //  16,777,216
  if (ws_size < 163577856) return;                           // need ~156 MiB

  // allow 96 KiB dynamic LDS (host-side calls, safe under graph capture)
  hipFuncSetAttribute((const void*)gemm_nt<7168, 4096, true>,
                      hipFuncAttributeMaxDynamicSharedMemorySize, 98304);
  hipFuncSetAttribute((const void*)gemm_nt<2048, 7168, false>,
                      hipFuncAttributeMaxDynamicSharedMemorySize, 98304);

  // 1) cast inputs to bf16 (wug with 64-row gate/up interleave permutation)
  cvt_f32_to_bf16<<<2048, 256, 0, stream>>>(x,   xb,  M * K / 4);
  cvt_wug_perm  <<<2048, 256, 0, stream>>>(wug, wub, 2 * E * K / 4);
  cvt_f32_to_bf16<<<1024, 256, 0, stream>>>(wd,  wdb, K * E / 4);

  // 2) h = swiglu(x @ w_up_gate^T) fused   [4096, 2048] bf16  (16x16 = 256 blocks)
  gemm_nt<7168, 4096, true><<<256, 256, 98304, stream>>>(xb, wub, h);

  // 3) out = h @ w_down^T     [4096, 7168] fp32  (16x28 = 448 blocks)
  gemm_nt<2048, 7168, false><<<448, 256, 98304, stream>>>(h, wdb, out);
}

// Round 7
// 405.574 us; speedup vs baseline: 1.1814x; 1.1814x over previous
//
#include <hip/hip_runtime.h>
#include <hip/hip_bf16.h>
#include <stdint.h>

// ---------- types ----------
typedef __attribute__((ext_vector_type(8))) short     bf16x8;  // MFMA A/B frag (4 VGPR)
typedef __attribute__((ext_vector_type(4))) float     f32x4;   // MFMA C/D frag

__device__ __forceinline__ unsigned short f2bf(float f) {
  unsigned int u = __float_as_uint(f);
  u += 0x7FFFu + ((u >> 16) & 1u);   // round-to-nearest-even
  return (unsigned short)(u >> 16);
}

__device__ __forceinline__ void async_cp16(const void* g, void* l) {
  __builtin_amdgcn_global_load_lds((const __attribute__((address_space(1))) void*)g,
                                   (__attribute__((address_space(3))) void*)l,
                                   16, 0, 0);
}

// ---------- fp32 -> bf16 conversion (memory-bound, vectorized) ----------
__global__ __launch_bounds__(256) void cvt_f32_to_bf16(const float* __restrict__ in,
                                                       unsigned short* __restrict__ out,
                                                       int n4) {
  int i = blockIdx.x * blockDim.x + threadIdx.x;
  const int stride = gridDim.x * blockDim.x;
  for (; i < n4; i += stride) {
    const float4 v = ((const float4*)in)[i];
    ushort4 o;
    o.x = f2bf(v.x); o.y = f2bf(v.y); o.z = f2bf(v.z); o.w = f2bf(v.w);
    ((ushort4*)out)[i] = o;
  }
}

// ---------- fp32 -> bf16 with gate/up row interleave ----------
// out row r: g = r>>5, w = r&31; src = g*16 + (w&15) + (w>=16 ? 2048 : 0)
// -> each 32-row group = 16 gate rows + 16 up rows of the same e-block.
__global__ __launch_bounds__(256) void cvt_wug_perm(const float* __restrict__ in,
                                                    unsigned short* __restrict__ out,
                                                    int n4) {            // 4096*1792
  int i = blockIdx.x * blockDim.x + threadIdx.x;
  const int stride = gridDim.x * blockDim.x;
  for (; i < n4; i += stride) {
    const int r = i / 1792, c = i - r * 1792;
    const int g = r >> 5, w = r & 31;
    const int src = g * 16 + (w & 15) + ((w & 16) ? 2048 : 0);
    const float4 v = ((const float4*)in)[(size_t)src * 1792 + c];
    ushort4 o;
    o.x = f2bf(v.x); o.y = f2bf(v.y); o.z = f2bf(v.z); o.w = f2bf(v.w);
    ((ushort4*)out)[(size_t)r * 1792 + c] = o;
  }
}

// ---------- 256x256 phase-interleaved NT bf16 GEMM (round-3 + m201 phases) --
// C[m,n] = sum_k A[m,k]*B[n,k].  512 thr = 8 waves (2Mx4N), wave-tile 128x64.
// LDS ring-4 at kstep (BK=32) granularity: slot = 16K A + 16K B, 128 KiB.
// Each kstep h = 2 phases (m201 granularity: 16 MFMA, 8/4 ds_reads, 2 gloads):
//   ph0: {read B n0..3 + A mh0 | STAGE_A(h+3)} -> bar -> lgkm0 -> 16 MFMA -> bar
//   ph1: {read A mh1           | STAGE_B(h+3)} -> bar -> lgkm0 -> 16 MFMA
//        -> vmcnt(8) -> bar
// Phase p+1's reads issue while phase p's MFMAs drain (~310 cyc/SIMD) -> the
// matrix pipe stays fed (the round-3 52% stall was read/MFMA lockstep bunching).
// vmcnt(8) counted (never 0): leaves ksteps h+2,h+3 in flight, h+1 guaranteed.
// Ring-4: stage slot (h+3)&3 was last read in kstep h-1 (barrier-separated).
// Swizzle (proven 0-conflict): line L (128B) = rows 2L,2L+1; 16B-slot p holds
// logical q = p ^ (L&7); staging pre-swizzles the per-lane GLOBAL source, LDS
// dest stays linear (m173).
// FUSE_SWIGLU: B rows pre-permuted so acc n in {0,2}=gate, {1,3}=up of the
// same e-cols -> h = silu(g)*u in-lane, write [M, N/2] bf16.
template <int K, int N, bool FUSE_SWIGLU>
__global__ __launch_bounds__(512, 2) void gemm_nt(const unsigned short* __restrict__ A,
                                                  const unsigned short* __restrict__ B,
                                                  void* __restrict__ Cv) {
  extern __shared__ char sm[];   // 131072 bytes: [4 slots x 16KB A][4 slots x 16KB B]
  constexpr int nbx = N / 256;
  constexpr int nwg = (4096 / 256) * nbx;
  constexpr size_t K2 = (size_t)K * 2;

  // T1: bijective XCD swizzle (nwg % 8 == 0 for both GEMMs)
  const int bid = blockIdx.x;
  constexpr int q8 = nwg / 8;
  const int swz = (bid & 7) * q8 + (bid >> 3);
  const int bx = swz % nbx, by = swz / nbx;
  const int row0 = by * 256, col0 = bx * 256;

  const int tid = threadIdx.x, wave = tid >> 6, lane = tid & 63;
  const int wr = wave >> 2, wc = wave & 3;       // wave 2x4 grid
  const int fr = lane & 15, fg = lane >> 4;      // fragment row / k-group

  // ---- staging addresses (pre-swizzled global source, linear LDS dest) ----
  const int l3 = lane >> 3;                 // 0..7
  const int q  = (lane & 7) ^ l3;           // 0..7 involution
  const int qr = q >> 2;                    // row parity
  const int qc = (q & 3) * 16;              // byte offset within kstep's 64B row
  const char* gA[2]; const char* gB[2];
#pragma unroll
  for (int i = 0; i < 2; ++i) {
    const int L = i * 64 + wave * 8 + l3;   // LDS line 0..127
    gA[i] = (const char*)A + (size_t)(row0 + 2 * L + qr) * K2 + qc;
    gB[i] = (const char*)B + (size_t)(col0 + 2 * L + qr) * K2 + qc;
  }

  // ---- fragment read offsets (swizzled) ----
  const int rbA = wr * 128 + fr;
  const int offA0 = (rbA >> 1) * 128 + (((((rbA & 1) << 2) | fg) ^ ((rbA >> 1) & 7)) << 4);
  const int rbB = wc * 64 + fr;
  const int offB0 = (rbB >> 1) * 128 + (((((rbB & 1) << 2) | fg) ^ ((rbB >> 1) & 7)) << 4);

  f32x4 acc[8][4];
#pragma unroll
  for (int m = 0; m < 8; ++m)
#pragma unroll
    for (int n = 0; n < 4; ++n) acc[m][n] = (f32x4){0.f, 0.f, 0.f, 0.f};

  constexpr int nh = K / 32;    // ksteps

#define STAGE_A(h, slot) do {                                   \
    char* d_ = sm + (slot) * 16384 + wave * 1024;               \
    async_cp16(gA[0] + (size_t)(h) * 64, d_);                   \
    async_cp16(gA[1] + (size_t)(h) * 64, d_ + 8192);            \
  } while (0)
#define STAGE_B(h, slot) do {                                   \
    char* d_ = sm + 65536 + (slot) * 16384 + wave * 1024;       \
    async_cp16(gB[0] + (size_t)(h) * 64, d_);                   \
    async_cp16(gB[1] + (size_t)(h) * 64, d_ + 8192);            \
  } while (0)

  // prologue: stage ksteps 0,1,2 (12 loads in flight); drain kstep 0's 4
#pragma unroll
  for (int hp = 0; hp < 3; ++hp) { STAGE_A(hp, hp); STAGE_B(hp, hp); }
  asm volatile("s_waitcnt vmcnt(8)" ::: "memory");
  __builtin_amdgcn_s_barrier();

  // invariant at kstep h top: slot h&3 resident; h+1, h+2 stages in flight
  for (int h = 0; h < nh; ++h) {
    const int slot = h & 3;
    const char* aBase = sm + slot * 16384;
    const char* bBase = sm + 65536 + slot * 16384;
    const int hs = (h + 3 < nh) ? h + 3 : nh - 1;   // clamped tail keeps vmcnt discipline
    const int sslot = (h + 3) & 3;                  // last read in kstep h-1 (pre-barrier)

    bf16x8 af[4], bfr[4];

    // ---- phase 0: read B(all n) + A(mh0); stage A(h+3); MFMA mh0 ----
#pragma unroll
    for (int n = 0; n < 4; ++n) bfr[n] = *(const bf16x8*)(bBase + offB0 + n * 1024);
#pragma unroll
    for (int m = 0; m < 4; ++m) af[m] = *(const bf16x8*)(aBase + offA0 + m * 1024);
    STAGE_A(hs, sslot);
    __builtin_amdgcn_s_barrier();
    asm volatile("s_waitcnt lgkmcnt(0)" ::: "memory");
    __builtin_amdgcn_sched_barrier(0);              // rule 18: pin MFMA below lgkm wait
    __builtin_amdgcn_s_setprio(1);
#pragma unroll
    for (int m = 0; m < 4; ++m)
#pragma unroll
      for (int n = 0; n < 4; ++n)
        acc[m][n] = __builtin_amdgcn_mfma_f32_16x16x32_bf16(af[m], bfr[n], acc[m][n], 0, 0, 0);
    __builtin_amdgcn_s_setprio(0);
    __builtin_amdgcn_s_barrier();

    // ---- phase 1: read A(mh1); stage B(h+3); MFMA mh1; vmcnt(8) ----
#pragma unroll
    for (int m = 0; m < 4; ++m) af[m] = *(const bf16x8*)(aBase + offA0 + (m + 4) * 1024);
    STAGE_B(hs, sslot);
    __builtin_amdgcn_s_barrier();
    asm volatile("s_waitcnt lgkmcnt(0)" ::: "memory");
    __builtin_amdgcn_sched_barrier(0);
    __builtin_amdgcn_s_setprio(1);
#pragma unroll
    for (int m = 0; m < 4; ++m)
#pragma unroll
      for (int n = 0; n < 4; ++n)
        acc[m + 4][n] = __builtin_amdgcn_mfma_f32_16x16x32_bf16(af[m], bfr[n], acc[m + 4][n], 0, 0, 0);
    __builtin_amdgcn_s_setprio(0);
    asm volatile("s_waitcnt vmcnt(8)" ::: "memory");  // kstep h+1's 4 loads drained
    __builtin_amdgcn_s_barrier();
  }
#undef STAGE_A
#undef STAGE_B

  // ---- epilogue: C/D layout col = lane&15, row = (lane>>4)*4 + j (m89-verified) ----
  const int rowb = row0 + wr * 128 + fg * 4;
  if (FUSE_SWIGLU) {
    // acc n in {0,2}: gate; {1,3}: up, same e-cols (pre-permuted B)
    unsigned short* Hp = (unsigned short*)Cv;
    const int ecb = ((col0 + wc * 64) >> 1) + fr;
#pragma unroll
    for (int m = 0; m < 8; ++m)
#pragma unroll
      for (int p = 0; p < 2; ++p)
#pragma unroll
        for (int j = 0; j < 4; ++j) {
          const float gv = acc[m][2 * p][j];
          const float uv = acc[m][2 * p + 1][j];
          const float s  = gv / (1.0f + __expf(-gv));
          Hp[(size_t)(rowb + m * 16 + j) * (N / 2) + (ecb + p * 16)] = f2bf(s * uv);
        }
  } else {
    float* Cp = (float*)Cv;
    const int colb = col0 + wc * 64 + fr;
#pragma unroll
    for (int m = 0; m < 8; ++m)
#pragma unroll
      for (int n = 0; n < 4; ++n)
#pragma unroll
        for (int j = 0; j < 4; ++j)
          Cp[(size_t)(rowb + m * 16 + j) * N + (colb + n * 16)] = acc[m][n][j];
  }
}

// ---------- launch ----------
extern "C" void kernel_launch(void* const* d_in, const int* in_sizes, int n_in,
                              void* d_out, int out_size, void* d_ws, size_t ws_size,
                              hipStream_t stream) {
  const int M = 4096, K = 7168, E = 2048;

  const float* x   = (const float*)d_in[0];  // [M,K]
  const float* wug = (const float*)d_in[1];  // [2E,K]
  const float* wd  = (const float*)d_in[2];  // [K,E]
  float* out = (float*)d_out;                // [M,K]

  // workspace layout (bytes)
  char* ws = (char*)d_ws;
  unsigned short* xb  = (unsigned short*)(ws);               //  58,720,256
  unsigned short* wub = (unsigned short*)(ws + 58720256);    //  58,720,256 (permuted)
  unsigned short* wdb = (unsigned short*)(ws + 117440512);   //  29,360,128
  unsigned short* h   = (unsigned short*)(ws + 146800640);   //  16,777,216
  if (ws_size < 163577856) return;                           // need ~156 MiB

  // allow 128 KiB dynamic LDS (host-side calls, safe under graph capture)
  hipFuncSetAttribute((const void*)gemm_nt<7168, 4096, true>,
                      hipFuncAttributeMaxDynamicSharedMemorySize, 131072);
  hipFuncSetAttribute((const void*)gemm_nt<2048, 7168, false>,
                      hipFuncAttributeMaxDynamicSharedMemorySize, 131072);

  // 1) cast inputs to bf16 (wug with gate/up interleave permutation)
  cvt_f32_to_bf16<<<2048, 256, 0, stream>>>(x,   xb,  M * K / 4);
  cvt_wug_perm  <<<2048, 256, 0, stream>>>(wug, wub, 2 * E * K / 4);
  cvt_f32_to_bf16<<<1024, 256, 0, stream>>>(wd,  wdb, K * E / 4);

  // 2) h = swiglu(x @ w_up_gate^T) fused   [4096, 2048] bf16  (16x16 = 256 blocks)
  gemm_nt<7168, 4096, true><<<256, 512, 131072, stream>>>(xb, wub, h);

  // 3) out = h @ w_down^T     [4096, 7168] fp32  (16x28 = 448 blocks)
  gemm_nt<2048, 7168, false><<<448, 512, 131072, stream>>>(h, wdb, out);
}